// Round 10
// baseline (993.484 us; speedup 1.0000x reference)
//
#include <hip/hip_runtime.h>

typedef __attribute__((ext_vector_type(8))) short short8;
typedef __attribute__((ext_vector_type(4))) float f32x4;

__device__ __forceinline__ ushort f2bf(float f){
    union { float f; unsigned u; } v; v.f = f;
    unsigned r = (v.u + 0x7fffu + ((v.u >> 16) & 1u)) >> 16;
    return (ushort)r;
}
__device__ __forceinline__ float bf2f(ushort u){
    union { unsigned u; float f; } v; v.u = ((unsigned)u) << 16;
    return v.f;
}

// ---------------- Layer 1: Cin=1 -> 40 real (stored 64, pad zero), direct fp32 ----------
__global__ __launch_bounds__(256) void conv_l1(
    const float* __restrict__ x, const float* __restrict__ w,
    const float* __restrict__ bias, ushort* __restrict__ out)
{
    __shared__ float xs[2916];     // [3][3][18][18] padded neighborhood
    __shared__ float wsh[3240];    // [40][81]
    const int tid = threadIdx.x;
    const int bx = blockIdx.x;
    const int d2 = bx & 15, d1 = (bx >> 4) & 15, b = bx >> 8;
    const float* xb = x + (size_t)b * 65536;

    for (int i = tid; i < 2916; i += 256){
        int i4 = i % 18; int r1 = i / 18; int i3 = r1 % 18;
        int r2 = r1 / 18; int a2 = r2 % 3; int a1 = r2 / 3;
        int e1 = d1 + a1 - 1, e2 = d2 + a2 - 1, e3 = i3 - 1, e4 = i4 - 1;
        float v = 0.f;
        if ((unsigned)e1 < 16u && (unsigned)e2 < 16u && (unsigned)e3 < 16u && (unsigned)e4 < 16u)
            v = xb[((e1 * 16 + e2) * 16 + e3) * 16 + e4];
        xs[i] = v;
    }
    for (int i = tid; i < 3240; i += 256) wsh[i] = w[i];
    __syncthreads();

    const int d3 = tid >> 4, d4 = tid & 15;
    float acc[40];
    #pragma unroll
    for (int c = 0; c < 40; ++c) acc[c] = 0.f;

    for (int t1 = 0; t1 < 3; ++t1)
    for (int t2 = 0; t2 < 3; ++t2)
    for (int t3 = 0; t3 < 3; ++t3)
    #pragma unroll
    for (int t4 = 0; t4 < 3; ++t4){
        float xv = xs[((t1 * 3 + t2) * 18 + d3 + t3) * 18 + d4 + t4];
        int tap = ((t1 * 3 + t2) * 3 + t3) * 3 + t4;
        #pragma unroll
        for (int c = 0; c < 40; ++c) acc[c] += wsh[c * 81 + tap] * xv;
    }

    ushort* ob = out + ((size_t)bx * 256 + tid) * 64;
    #pragma unroll
    for (int c = 0; c < 40; ++c){
        float v = acc[c] + bias[c]; v = v > 0.f ? v : 0.f;
        ob[c] = f2bf(v);
    }
    #pragma unroll
    for (int c = 40; c < 64; ++c) ob[c] = 0;
}

// ---------------- Layer 6: 40 real (stored 48) -> Cout=1, direct fp32 -------------------
__global__ __launch_bounds__(256) void conv_l6(
    const ushort* __restrict__ in, const float* __restrict__ w,
    const float* __restrict__ bias, float* __restrict__ out)
{
    __shared__ float wsh[3240];    // [ci=40][81]
    const int tid = threadIdx.x;
    const int bx = blockIdx.x;
    const int d2 = bx & 15, d1 = (bx >> 4) & 15, b = bx >> 8;
    for (int i = tid; i < 3240; i += 256) wsh[i] = w[i];
    __syncthreads();

    const int d3 = tid >> 4, d4 = tid & 15;
    const ushort* inb = in + (size_t)b * 65536 * 48;
    float acc = 0.f;
    for (int t1 = 0; t1 < 3; ++t1){
        int e1 = d1 + t1 - 1; if ((unsigned)e1 >= 16u) continue;
        for (int t2 = 0; t2 < 3; ++t2){
            int e2 = d2 + t2 - 1; if ((unsigned)e2 >= 16u) continue;
            for (int t3 = 0; t3 < 3; ++t3){
                int e3 = d3 + t3 - 1; if ((unsigned)e3 >= 16u) continue;
                for (int t4 = 0; t4 < 3; ++t4){
                    int e4 = d4 + t4 - 1; if ((unsigned)e4 >= 16u) continue;
                    const ushort* p = inb + (size_t)(((e1 * 16 + e2) * 16 + e3) * 16 + e4) * 48;
                    int tap = ((t1 * 3 + t2) * 3 + t3) * 3 + t4;
                    #pragma unroll
                    for (int c8 = 0; c8 < 5; ++c8){
                        short8 v = *(const short8*)(p + c8 * 8);
                        #pragma unroll
                        for (int j = 0; j < 8; ++j)
                            acc += bf2f((ushort)v[j]) * wsh[(c8 * 8 + j) * 81 + tap];
                    }
                }
            }
        }
    }
    float v = acc + bias[0]; v = v > 0.f ? v : 0.f;
    out[(size_t)bx * 256 + tid] = v;
}

// ---------------- Weight repack: [co][ci][81] fp32 -> [81][ci/8][co][8] bf16 ------------
__global__ void repack_w(const float* __restrict__ w, ushort* __restrict__ wp,
                         int cin, int cout, int cin_s, int cout_c)
{
    const int total = 81 * cin_s * cout_c;
    for (int i = blockIdx.x * blockDim.x + threadIdx.x; i < total; i += gridDim.x * blockDim.x){
        int j = i & 7;
        int rest = i >> 3;
        int co = rest % cout_c;
        int rest2 = rest / cout_c;
        int ci_hi = rest2 % (cin_s >> 3);
        int t = rest2 / (cin_s >> 3);
        int ci = ci_hi * 8 + j;
        float v = (ci < cin && co < cout) ? w[((size_t)co * cin + ci) * 81 + t] : 0.f;
        wp[i] = f2bf(v);
    }
}

// ---------------- 16x16x32 MFMA implicit-GEMM conv layer --------------------------------
// in : [b][d1][d2][d3][d4][CIN_S]  bf16
// wp : [81][ci/8][COUT_TOT][8]     bf16 (B-fragment native)
// out: [b][d1][d2][d3][d4][OST]    bf16; cols [CREAL,OST) zero-filled explicitly (PADC>0)
// Block: 256 thr = 4 waves; wave tile M64 x N=COUT_W (m4 x NT of 16x16x32).
// A chunk [256 pos][32ch] XOR-swizzled + dbuf; B 3-tap chunk [12][COUT_W] XOR-swizzled +
// dbuf; both conflict-free (round-6/9 verified). Per-step sync is raw s_barrier +
// lgkmcnt(0) ONLY (T4): register-destination global prefetch loads stay in flight
// across the barrier instead of being drained by __syncthreads()'s vmcnt(0).
template<int CIN_S, int COUT_W, int COUT_TOT, int OST, int CREAL, int PADC>
__global__ __launch_bounds__(256, 2) void conv16(
    const ushort* __restrict__ in, const ushort* __restrict__ wp,
    const float* __restrict__ bias, ushort* __restrict__ out)
{
    constexpr int KC   = CIN_S / 32;           // A chunks per plane
    constexpr int NT   = COUT_W / 16;          // n-frags per wave
    constexpr int A8   = 1024;                 // 16B units per A chunk (256 pos x 4)
    constexpr int NLA  = A8 / 256;             // = 4
    constexpr int B8   = 12 * COUT_W;          // 16B units per 3-tap B chunk
    constexpr int NLB  = (B8 + 255) / 256;

    __shared__ __attribute__((aligned(16))) ushort As[2][8192];     // 2 x 16 KB
    __shared__ __attribute__((aligned(16))) ushort Bs[2][B8 * 8];

    const int tid  = threadIdx.x;
    const int lane = tid & 63;
    const int wm   = tid >> 6;                 // 0..3 (64-row M slice)
    const int r    = lane & 15;                // A-row offset / B-col / D-col
    const int g    = lane >> 4;                // k-group / D row-group

    // grid: [strips][512 plane blocks]; XCD-aware chunked swizzle on plane index
    const int p0 = blockIdx.x;
    const int strip = p0 >> 9;
    const int pp = p0 & 511;
    const int bx = (pp & 7) * 64 + (pp >> 3);
    const int d2 = bx & 15, d1 = (bx >> 4) & 15, b = bx >> 8;
    const int co_base = strip * COUT_W;

    const ushort* inb = in + (size_t)b * 65536 * CIN_S;

    // valid (t1,t2) groups packed 4 bits each
    unsigned long long gpack = 0ull; int ng = 0;
    #pragma unroll
    for (int gg = 0; gg < 9; ++gg){
        const int t1 = gg / 3, t2 = gg - (gg / 3) * 3;
        if ((unsigned)(d1 + t1 - 1) < 16u && (unsigned)(d2 + t2 - 1) < 16u){
            gpack |= ((unsigned long long)gg) << (ng * 4);
            ++ng;
        }
    }
    const int nchunk = ng * KC;
    const int nstep  = nchunk * 3;

    f32x4 acc[4][NT];
    #pragma unroll
    for (int mi = 0; mi < 4; ++mi)
        #pragma unroll
        for (int n = 0; n < NT; ++n)
            acc[mi][n] = (f32x4){0.f, 0.f, 0.f, 0.f};

    short8 areg[NLA];
    short8 brg0[NLB], brg1[NLB];

    auto loadAreg = [&](int c){
        const int gi = c / KC, kh = c - gi * KC;
        const int gg = (int)((gpack >> (gi * 4)) & 15ull);
        const int t1 = gg / 3, t2 = gg - t1 * 3;
        const ushort* src = inb + ((size_t)((d1 + t1 - 1) * 16 + (d2 + t2 - 1)) * 256) * CIN_S + kh * 32;
        #pragma unroll
        for (int k = 0; k < NLA; ++k){
            const int i = tid + k * 256;
            areg[k] = *(const short8*)(src + (size_t)(i >> 2) * CIN_S + (i & 3) * 8);
        }
    };
    auto writeA = [&](ushort* dst){
        #pragma unroll
        for (int k = 0; k < NLA; ++k){
            const int i = tid + k * 256;
            const int pos = i >> 2, gc = i & 3;
            const int gs = gc ^ ((pos >> 1) & 3);        // round-6 involution
            *(short8*)(dst + pos * 32 + gs * 8) = areg[k];
        }
    };
    auto loadBreg = [&](int s, short8 (&brg)[NLB]){
        const int c = s / 3, t3 = s - c * 3;
        const int gi = c / KC, kh = c - gi * KC;
        const int gg = (int)((gpack >> (gi * 4)) & 15ull);
        const int tap0 = gg * 9 + t3 * 3;          // t4 = 0
        #pragma unroll
        for (int k = 0; k < NLB; ++k){
            const int i = tid + k * 256;
            if (i < B8){
                const int t4 = i / (4 * COUT_W);
                const int rest = i - t4 * (4 * COUT_W);
                const int gk = rest / COUT_W;
                const int col = rest - gk * COUT_W;
                brg[k] = *((const short8*)wp +
                           ((size_t)(tap0 + t4) * (CIN_S / 8) + kh * 4 + gk) * COUT_TOT + co_base + col);
            }
        }
    };
    auto writeB = [&](ushort* dst, short8 (&brg)[NLB]){
        #pragma unroll
        for (int k = 0; k < NLB; ++k){
            const int i = tid + k * 256;
            if (i < B8){
                const int gk = (i / COUT_W) & 3;
                *(short8*)(dst + ((i * 8) ^ (gk << 3))) = brg[k];   // round-6 involution
            }
        }
    };

    // prologue
    loadAreg(0);
    loadBreg(0, brg0);
    writeA(As[0]);
    writeB(Bs[0], brg0);
    if (nchunk > 1) loadAreg(1);
    if (nstep > 1) loadBreg(1, brg1);
    __syncthreads();

    int c = 0, t3 = 0;
    for (int s = 0; s < nstep; ++s){
        // ds-write next B chunk (regs loaded 2 steps ago; compiler inserts the
        // counted vmcnt wait for exactly this batch)
        if (s + 1 < nstep){
            if ((s + 1) & 1) writeB(Bs[1], brg1); else writeB(Bs[0], brg0);
        }
        // ds-write next A chunk; refill areg 2 chunks ahead
        if (t3 == 0 && c + 1 < nchunk) writeA(As[(c + 1) & 1]);
        if (t3 == 1 && c + 2 < nchunk) loadAreg(c + 2);
        // issue global loads for B two steps ahead (stay in flight across barrier)
        if (s + 2 < nstep){
            if (s & 1) loadBreg(s + 2, brg1); else loadBreg(s + 2, brg0);
        }

        // compute: 3 t4-taps x (m4 x NT) MFMA, K=32 per step
        const ushort* Ab = As[c & 1];
        const ushort* Bb = Bs[s & 1];
        __builtin_amdgcn_s_setprio(1);
        #pragma unroll
        for (int t4 = 0; t4 < 3; ++t4){
            const int e4 = r + t4 - 1;
            const bool v4 = (unsigned)e4 < 16u;
            const int gsw = (g ^ ((e4 >> 1) & 3)) << 3;      // A swizzle (e3-independent)
            short8 bfr[NT];
            #pragma unroll
            for (int n = 0; n < NT; ++n)
                bfr[n] = *(const short8*)(Bb + ((((t4 * 4 + g) * COUT_W + n * 16 + r) * 8) ^ (g << 3)));
            #pragma unroll
            for (int mi = 0; mi < 4; ++mi){
                const int e3 = 4 * wm + mi + t3 - 1;
                short8 af = {0, 0, 0, 0, 0, 0, 0, 0};
                if (v4 && (unsigned)e3 < 16u)
                    af = *(const short8*)(Ab + (e3 * 16 + e4) * 32 + gsw);
                #pragma unroll
                for (int n = 0; n < NT; ++n)
                    acc[mi][n] = __builtin_amdgcn_mfma_f32_16x16x32_bf16(af, bfr[n], acc[mi][n], 0, 0, 0);
            }
        }
        __builtin_amdgcn_s_setprio(0);

        // T4 sync: ds ops drained (lgkmcnt only), global reg-loads stay in flight.
        asm volatile("s_waitcnt lgkmcnt(0)" ::: "memory");
        __builtin_amdgcn_s_barrier();
        __builtin_amdgcn_sched_barrier(0);

        ++t3; if (t3 == 3){ t3 = 0; ++c; }
    }

    // epilogue: bias + ReLU + bf16 store. D frag: col = lane&15, row = g*4 + reg
    float bv[NT];
    #pragma unroll
    for (int n = 0; n < NT; ++n){
        const int co = co_base + n * 16 + r;
        bv[n] = (co < CREAL) ? bias[co] : 0.f;
    }
    ushort* ob = out + (size_t)bx * 256 * OST;
    #pragma unroll
    for (int mi = 0; mi < 4; ++mi){
        #pragma unroll
        for (int n = 0; n < NT; ++n){
            const int co = co_base + n * 16 + r;
            #pragma unroll
            for (int j = 0; j < 4; ++j){
                const int row = 64 * wm + 16 * mi + g * 4 + j;
                float v = acc[mi][n][j] + bv[n];
                v = v > 0.f ? v : 0.f;
                ob[(size_t)row * OST + co] = f2bf(v);
            }
        }
    }
    if (PADC > 0){
        const int row = 64 * wm + lane;
        const short8 z = {0, 0, 0, 0, 0, 0, 0, 0};
        #pragma unroll
        for (int pc = 0; pc < PADC; pc += 8)
            *(short8*)(ob + (size_t)row * OST + CREAL + pc) = z;
    }
}

extern "C" void kernel_launch(void* const* d_in, const int* in_sizes, int n_in,
                              void* d_out, int out_size, void* d_ws, size_t ws_size,
                              hipStream_t stream) {
    const float* x  = (const float*)d_in[0];
    const float* w1 = (const float*)d_in[1];  const float* b1 = (const float*)d_in[2];
    const float* w2 = (const float*)d_in[3];  const float* b2 = (const float*)d_in[4];
    const float* w3 = (const float*)d_in[5];  const float* b3 = (const float*)d_in[6];
    const float* w4 = (const float*)d_in[7];  const float* b4 = (const float*)d_in[8];
    const float* w5 = (const float*)d_in[9];  const float* b5 = (const float*)d_in[10];
    const float* w6 = (const float*)d_in[11]; const float* b6 = (const float*)d_in[12];

    // workspace layout (bf16 ushorts):
    ushort* bufA = (ushort*)d_ws;                       // [131072][160] : 41.9 MB
    ushort* bufB = bufA + (size_t)131072 * 160;         // [131072][96]  : 25.2 MB
    ushort* wp2  = bufB + (size_t)131072 * 96;          // 81*8*80*8
    ushort* wp3  = wp2 + (size_t)81 * 64 * 80;          // 81*12*160*8
    ushort* wp4  = wp3 + (size_t)81 * 96 * 160;         // 81*20*80*8
    ushort* wp5  = wp4 + (size_t)81 * 160 * 80;         // 81*12*48*8

    repack_w<<<512, 256, 0, stream>>>(w2, wp2, 40, 80, 64, 80);
    repack_w<<<512, 256, 0, stream>>>(w3, wp3, 80, 160, 96, 160);
    repack_w<<<512, 256, 0, stream>>>(w4, wp4, 160, 80, 160, 80);
    repack_w<<<512, 256, 0, stream>>>(w5, wp5, 80, 40, 96, 48);

    conv_l1<<<512, 256, 0, stream>>>(x, w1, b1, bufA);
    //       CIN_S  W   TOT  OST  CREAL PADC
    conv16<  64,   80,  80,  96,  80,  16><<< 512, 256, 0, stream>>>(bufA, wp2, b2, bufB);
    conv16<  96,   80, 160, 160, 160,   0><<<1024, 256, 0, stream>>>(bufB, wp3, b3, bufA);
    conv16< 160,   80,  80,  96,  80,  16><<< 512, 256, 0, stream>>>(bufA, wp4, b4, bufB);
    conv16<  96,   48,  48,  48,  40,   0><<< 512, 256, 0, stream>>>(bufB, wp5, b5, bufA);
    conv_l6<<<512, 256, 0, stream>>>(bufA, w6, b6, (float*)d_out);
}

// Round 11
// 871.743 us; speedup vs baseline: 1.1397x; 1.1397x over previous
//
#include <hip/hip_runtime.h>

typedef __attribute__((ext_vector_type(8))) short short8;
typedef __attribute__((ext_vector_type(4))) float f32x4;

#define GLD16(gsrc, ldst) __builtin_amdgcn_global_load_lds( \
    (const __attribute__((address_space(1))) unsigned int*)(gsrc), \
    (__attribute__((address_space(3))) unsigned int*)(ldst), 16, 0, 0)

__device__ __forceinline__ ushort f2bf(float f){
    union { float f; unsigned u; } v; v.f = f;
    unsigned r = (v.u + 0x7fffu + ((v.u >> 16) & 1u)) >> 16;
    return (ushort)r;
}
__device__ __forceinline__ float bf2f(ushort u){
    union { unsigned u; float f; } v; v.u = ((unsigned)u) << 16;
    return v.f;
}

// ---------------- Layer 1: Cin=1 -> 40 real (stored 64, pad zero), direct fp32 ----------
__global__ __launch_bounds__(256) void conv_l1(
    const float* __restrict__ x, const float* __restrict__ w,
    const float* __restrict__ bias, ushort* __restrict__ out)
{
    __shared__ float xs[2916];     // [3][3][18][18] padded neighborhood
    __shared__ float wsh[3240];    // [40][81]
    const int tid = threadIdx.x;
    const int bx = blockIdx.x;
    const int d2 = bx & 15, d1 = (bx >> 4) & 15, b = bx >> 8;
    const float* xb = x + (size_t)b * 65536;

    for (int i = tid; i < 2916; i += 256){
        int i4 = i % 18; int r1 = i / 18; int i3 = r1 % 18;
        int r2 = r1 / 18; int a2 = r2 % 3; int a1 = r2 / 3;
        int e1 = d1 + a1 - 1, e2 = d2 + a2 - 1, e3 = i3 - 1, e4 = i4 - 1;
        float v = 0.f;
        if ((unsigned)e1 < 16u && (unsigned)e2 < 16u && (unsigned)e3 < 16u && (unsigned)e4 < 16u)
            v = xb[((e1 * 16 + e2) * 16 + e3) * 16 + e4];
        xs[i] = v;
    }
    for (int i = tid; i < 3240; i += 256) wsh[i] = w[i];
    __syncthreads();

    const int d3 = tid >> 4, d4 = tid & 15;
    float acc[40];
    #pragma unroll
    for (int c = 0; c < 40; ++c) acc[c] = 0.f;

    for (int t1 = 0; t1 < 3; ++t1)
    for (int t2 = 0; t2 < 3; ++t2)
    for (int t3 = 0; t3 < 3; ++t3)
    #pragma unroll
    for (int t4 = 0; t4 < 3; ++t4){
        float xv = xs[((t1 * 3 + t2) * 18 + d3 + t3) * 18 + d4 + t4];
        int tap = ((t1 * 3 + t2) * 3 + t3) * 3 + t4;
        #pragma unroll
        for (int c = 0; c < 40; ++c) acc[c] += wsh[c * 81 + tap] * xv;
    }

    ushort* ob = out + ((size_t)bx * 256 + tid) * 64;
    #pragma unroll
    for (int c = 0; c < 40; ++c){
        float v = acc[c] + bias[c]; v = v > 0.f ? v : 0.f;
        ob[c] = f2bf(v);
    }
    #pragma unroll
    for (int c = 40; c < 64; ++c) ob[c] = 0;
}

// ---------------- Layer 6: 40 real (stored 48) -> Cout=1, direct fp32 -------------------
__global__ __launch_bounds__(256) void conv_l6(
    const ushort* __restrict__ in, const float* __restrict__ w,
    const float* __restrict__ bias, float* __restrict__ out)
{
    __shared__ float wsh[3240];    // [ci=40][81]
    const int tid = threadIdx.x;
    const int bx = blockIdx.x;
    const int d2 = bx & 15, d1 = (bx >> 4) & 15, b = bx >> 8;
    for (int i = tid; i < 3240; i += 256) wsh[i] = w[i];
    __syncthreads();

    const int d3 = tid >> 4, d4 = tid & 15;
    const ushort* inb = in + (size_t)b * 65536 * 48;
    float acc = 0.f;
    for (int t1 = 0; t1 < 3; ++t1){
        int e1 = d1 + t1 - 1; if ((unsigned)e1 >= 16u) continue;
        for (int t2 = 0; t2 < 3; ++t2){
            int e2 = d2 + t2 - 1; if ((unsigned)e2 >= 16u) continue;
            for (int t3 = 0; t3 < 3; ++t3){
                int e3 = d3 + t3 - 1; if ((unsigned)e3 >= 16u) continue;
                for (int t4 = 0; t4 < 3; ++t4){
                    int e4 = d4 + t4 - 1; if ((unsigned)e4 >= 16u) continue;
                    const ushort* p = inb + (size_t)(((e1 * 16 + e2) * 16 + e3) * 16 + e4) * 48;
                    int tap = ((t1 * 3 + t2) * 3 + t3) * 3 + t4;
                    #pragma unroll
                    for (int c8 = 0; c8 < 5; ++c8){
                        short8 v = *(const short8*)(p + c8 * 8);
                        #pragma unroll
                        for (int j = 0; j < 8; ++j)
                            acc += bf2f((ushort)v[j]) * wsh[(c8 * 8 + j) * 81 + tap];
                    }
                }
            }
        }
    }
    float v = acc + bias[0]; v = v > 0.f ? v : 0.f;
    out[(size_t)bx * 256 + tid] = v;
}

// -------- Weight repack: [co][ci][81] fp32 -> wq[strip][chunk][1024 x 16B] bf16 ---------
// chunk = ((gg*KC + kh)*3 + t3); inside: logical unit u = [t4][gk][col] of the 3-tap
// B-chunk, stored PRE-SWIZZLED at physical unit u^gk (the conflict-free involution),
// so global_load_lds with a LINEAR dest yields the swizzled LDS layout for free.
__global__ void repack_wq(const float* __restrict__ w, ushort* __restrict__ wq,
                          int cin_real, int cout_real, int kc, int cout_w, int nstrip)
{
    const int ncc = 27 * kc;                  // 9 groups * kc * 3 t3
    const int total = nstrip * ncc * 8192;
    for (int o = blockIdx.x * blockDim.x + threadIdx.x; o < total; o += gridDim.x * blockDim.x){
        const int j = o & 7;
        const int u_phys = (o >> 3) & 1023;
        const int chunk = o >> 13;
        const int strip = chunk / ncc;
        const int cc = chunk - strip * ncc;
        const int gg = cc / (kc * 3);
        const int rem = cc - gg * (kc * 3);
        const int kh = rem / 3;
        const int t3 = rem - kh * 3;
        float v = 0.f;
        if (u_phys < 12 * cout_w){
            const int per = 4 * cout_w;
            const int gk = ((u_phys % per) / cout_w) & 3;
            const int u = u_phys ^ gk;        // involution: gk(u) == gk(u_phys)
            const int t4 = u / per;
            const int rest = u - t4 * per;
            const int gk2 = rest / cout_w;
            const int col = rest - gk2 * cout_w;
            const int tap = gg * 9 + t3 * 3 + t4;
            const int ci = kh * 32 + gk2 * 8 + j;
            const int co = strip * cout_w + col;
            if (ci < cin_real && co < cout_real)
                v = w[((size_t)co * cin_real + ci) * 81 + tap];
        }
        wq[o] = f2bf(v);
    }
}

// ---------------- 16x16x32 MFMA implicit-GEMM conv layer --------------------------------
// in : [b][d1][d2][d3][d4][CIN_S]  bf16
// wq : pre-swizzled chunk layout (see repack_wq)
// out: [b][d1][d2][d3][d4][OST]    bf16; cols [CREAL,OST) zero-filled (PADC>0)
// Block: 256 thr = 4 waves; wave tile M64 x N=COUT_W (m4 x NT of 16x16x32).
// ALL staging via global_load_lds (no register round-trip): B linear from wq (pre-swz),
// A with per-lane pre-swizzled source addresses. m201-style step:
//   issue gloads(s+1) -> s_waitcnt vmcnt(4|8) -> s_barrier -> ds_read+MFMA -> s_barrier
// Loads stay in flight a full step; no vmcnt(0) in the loop; end barrier makes the
// next step's overwrite-issue safe (all readers of that buffer are past it).
template<int CIN_S, int COUT_W, int OST, int CREAL, int PADC>
__global__ __launch_bounds__(256, 2) void conv16(
    const ushort* __restrict__ in, const ushort* __restrict__ wq,
    const float* __restrict__ bias, ushort* __restrict__ out)
{
    constexpr int KC  = CIN_S / 32;            // A chunks per plane
    constexpr int NT  = COUT_W / 16;           // n-frags per wave
    constexpr int NCC = 27 * KC;               // B chunks per strip

    __shared__ __attribute__((aligned(16))) ushort As[2][8192];   // 2 x 16 KB
    __shared__ __attribute__((aligned(16))) ushort Bs[2][8192];   // 2 x 16 KB

    const int tid  = threadIdx.x;
    const int lane = tid & 63;
    const int wm   = tid >> 6;                 // 0..3 (64-row M slice)
    const int r    = lane & 15;                // A-row offset / B-col / D-col
    const int g    = lane >> 4;                // k-group / D row-group

    // grid: [strips][512 plane blocks]; XCD-aware chunked swizzle on plane index
    const int p0 = blockIdx.x;
    const int strip = p0 >> 9;
    const int pp = p0 & 511;
    const int bx = (pp & 7) * 64 + (pp >> 3);
    const int d2 = bx & 15, d1 = (bx >> 4) & 15, b = bx >> 8;
    const int co_base = strip * COUT_W;

    const ushort* inb = in + (size_t)b * 65536 * CIN_S;
    const ushort* wqs = wq + ((size_t)strip * NCC << 13);

    // valid (t1,t2) groups packed 4 bits each
    unsigned long long gpack = 0ull; int ng = 0;
    #pragma unroll
    for (int gg = 0; gg < 9; ++gg){
        const int t1 = gg / 3, t2 = gg - (gg / 3) * 3;
        if ((unsigned)(d1 + t1 - 1) < 16u && (unsigned)(d2 + t2 - 1) < 16u){
            gpack |= ((unsigned long long)gg) << (ng * 4);
            ++ng;
        }
    }
    const int nchunk = ng * KC;
    const int nstep  = nchunk * 3;

    f32x4 acc[4][NT];
    #pragma unroll
    for (int mi = 0; mi < 4; ++mi)
        #pragma unroll
        for (int n = 0; n < NT; ++n)
            acc[mi][n] = (f32x4){0.f, 0.f, 0.f, 0.f};

    const int ubase = (tid >> 6) * 256;        // wave-uniform
    const int ul = tid & 63;

    // B chunk: 1024 x 16B, linear copy (pre-swizzled in wq)
    auto issueB = [&](int sn, ushort* dst){
        const int cc = sn / 3, tt = sn - cc * 3;
        const int gi = cc / KC, kh = cc - gi * KC;
        const int gg = (int)((gpack >> (gi * 4)) & 15ull);
        const ushort* src = wqs + ((size_t)((gg * KC + kh) * 3 + tt) << 13);
        #pragma unroll
        for (int k = 0; k < 4; ++k){
            const int u0 = ubase + k * 64;     // wave-uniform dest base
            GLD16(src + (size_t)(u0 + ul) * 8, dst + u0 * 8);
        }
    };
    // A chunk: [256 pos][32 ch] = 1024 x 16B; per-lane pre-swizzled SOURCE address so the
    // linear LDS dest realizes the conflict-free layout the read side expects.
    auto issueA = [&](int cn, ushort* dst){
        const int gi = cn / KC, kh = cn - gi * KC;
        const int gg = (int)((gpack >> (gi * 4)) & 15ull);
        const int t1 = gg / 3, t2 = gg - t1 * 3;
        const ushort* src = inb + ((size_t)((d1 + t1 - 1) * 16 + (d2 + t2 - 1)) * 256) * CIN_S + kh * 32;
        #pragma unroll
        for (int k = 0; k < 4; ++k){
            const int u0 = ubase + k * 64;
            const int u = u0 + ul;
            const int pos = u >> 2;
            const int gc = (u & 3) ^ ((u >> 3) & 3);
            GLD16(src + (size_t)pos * CIN_S + gc * 8, dst + u0 * 8);
        }
    };

    // prologue: chunk 0 A + step 0 B staged, full drain once
    issueA(0, As[0]);
    issueB(0, Bs[0]);
    asm volatile("s_waitcnt vmcnt(0)" ::: "memory");
    __builtin_amdgcn_s_barrier();
    __builtin_amdgcn_sched_barrier(0);

    int c = 0, t3 = 0;
    for (int s = 0; s < nstep; ++s){
        // issue prefetch for s+1 (and next A chunk at chunk starts)
        int nis = 0;
        if (s + 1 < nstep){ issueB(s + 1, Bs[(s + 1) & 1]); nis += 4; }
        if (t3 == 0 && c + 1 < nchunk){ issueA(c + 1, As[(c + 1) & 1]); nis += 4; }
        // counted wait: previous step's loads (for THIS step's buffers) complete;
        // the nis just-issued stay in flight across the barrier and the MFMA.
        if (nis == 8)      asm volatile("s_waitcnt vmcnt(8)" ::: "memory");
        else if (nis == 4) asm volatile("s_waitcnt vmcnt(4)" ::: "memory");
        else               asm volatile("s_waitcnt vmcnt(0)" ::: "memory");
        __builtin_amdgcn_s_barrier();
        __builtin_amdgcn_sched_barrier(0);

        // compute: 3 t4-taps x (m4 x NT) MFMA, K=32 per step
        const ushort* Ab = As[c & 1];
        const ushort* Bb = Bs[s & 1];
        __builtin_amdgcn_s_setprio(1);
        #pragma unroll
        for (int t4 = 0; t4 < 3; ++t4){
            const int e4 = r + t4 - 1;
            const bool v4 = (unsigned)e4 < 16u;
            const int gsw = (g ^ ((e4 >> 1) & 3)) << 3;      // A swizzle (e3-independent)
            short8 bfr[NT];
            #pragma unroll
            for (int n = 0; n < NT; ++n)
                bfr[n] = *(const short8*)(Bb + ((((t4 * 4 + g) * COUT_W + n * 16 + r) * 8) ^ (g << 3)));
            #pragma unroll
            for (int mi = 0; mi < 4; ++mi){
                const int e3 = 4 * wm + mi + t3 - 1;
                short8 af = {0, 0, 0, 0, 0, 0, 0, 0};
                if (v4 && (unsigned)e3 < 16u)
                    af = *(const short8*)(Ab + (e3 * 16 + e4) * 32 + gsw);
                #pragma unroll
                for (int n = 0; n < NT; ++n)
                    acc[mi][n] = __builtin_amdgcn_mfma_f32_16x16x32_bf16(af, bfr[n], acc[mi][n], 0, 0, 0);
            }
        }
        __builtin_amdgcn_s_setprio(0);

        // end barrier: all readers of this step's buffers are done before any wave
        // issues the overwriting gloads at the next step's top.
        __builtin_amdgcn_sched_barrier(0);
        __builtin_amdgcn_s_barrier();
        __builtin_amdgcn_sched_barrier(0);

        ++t3; if (t3 == 3){ t3 = 0; ++c; }
    }

    // epilogue: bias + ReLU + bf16 store. D frag: col = lane&15, row = g*4 + reg
    float bv[NT];
    #pragma unroll
    for (int n = 0; n < NT; ++n){
        const int co = co_base + n * 16 + r;
        bv[n] = (co < CREAL) ? bias[co] : 0.f;
    }
    ushort* ob = out + (size_t)bx * 256 * OST;
    #pragma unroll
    for (int mi = 0; mi < 4; ++mi){
        #pragma unroll
        for (int n = 0; n < NT; ++n){
            const int co = co_base + n * 16 + r;
            #pragma unroll
            for (int j = 0; j < 4; ++j){
                const int row = 64 * wm + 16 * mi + g * 4 + j;
                float v = acc[mi][n][j] + bv[n];
                v = v > 0.f ? v : 0.f;
                ob[(size_t)row * OST + co] = f2bf(v);
            }
        }
    }
    if (PADC > 0){
        const int row = 64 * wm + lane;
        const short8 z = {0, 0, 0, 0, 0, 0, 0, 0};
        #pragma unroll
        for (int pc = 0; pc < PADC; pc += 8)
            *(short8*)(ob + (size_t)row * OST + CREAL + pc) = z;
    }
}

extern "C" void kernel_launch(void* const* d_in, const int* in_sizes, int n_in,
                              void* d_out, int out_size, void* d_ws, size_t ws_size,
                              hipStream_t stream) {
    const float* x  = (const float*)d_in[0];
    const float* w1 = (const float*)d_in[1];  const float* b1 = (const float*)d_in[2];
    const float* w2 = (const float*)d_in[3];  const float* b2 = (const float*)d_in[4];
    const float* w3 = (const float*)d_in[5];  const float* b3 = (const float*)d_in[6];
    const float* w4 = (const float*)d_in[7];  const float* b4 = (const float*)d_in[8];
    const float* w5 = (const float*)d_in[9];  const float* b5 = (const float*)d_in[10];
    const float* w6 = (const float*)d_in[11]; const float* b6 = (const float*)d_in[12];

    // workspace layout (bf16 ushorts): activations + pre-swizzled weight chunks
    ushort* bufA = (ushort*)d_ws;                       // [131072][160] : 41.9 MB
    ushort* bufB = bufA + (size_t)131072 * 160;         // [131072][96]  : 25.2 MB
    ushort* wq2  = bufB + (size_t)131072 * 96;          //  54 chunks * 8192
    ushort* wq3  = wq2 + (size_t)54  * 8192;            // 162 chunks * 8192 (2 strips)
    ushort* wq4  = wq3 + (size_t)162 * 8192;            // 135 chunks * 8192
    ushort* wq5  = wq4 + (size_t)135 * 8192;            //  81 chunks * 8192

    //                                      cin  cout  kc  cout_w  nstrip
    repack_wq<<<512, 256, 0, stream>>>(w2, wq2,  40,  80, 2, 80, 1);
    repack_wq<<<512, 256, 0, stream>>>(w3, wq3,  80, 160, 3, 80, 2);
    repack_wq<<<512, 256, 0, stream>>>(w4, wq4, 160,  80, 5, 80, 1);
    repack_wq<<<512, 256, 0, stream>>>(w5, wq5,  80,  40, 3, 48, 1);

    conv_l1<<<512, 256, 0, stream>>>(x, w1, b1, bufA);
    //       CIN_S  W   OST  CREAL PADC
    conv16<  64,   80,  96,  80,  16><<< 512, 256, 0, stream>>>(bufA, wq2, b2, bufB);
    conv16<  96,   80, 160, 160,   0><<<1024, 256, 0, stream>>>(bufB, wq3, b3, bufA);
    conv16< 160,   80,  96,  80,  16><<< 512, 256, 0, stream>>>(bufA, wq4, b4, bufB);
    conv16<  96,   48,  48,  40,   0><<< 512, 256, 0, stream>>>(bufB, wq5, b5, bufA);
    conv_l6<<<512, 256, 0, stream>>>(bufA, w6, b6, (float*)d_out);
}

// Round 12
// 815.057 us; speedup vs baseline: 1.2189x; 1.0695x over previous
//
#include <hip/hip_runtime.h>

typedef __attribute__((ext_vector_type(8))) short short8;
typedef __attribute__((ext_vector_type(4))) float f32x4;

#define GLD16(gsrc, ldst) __builtin_amdgcn_global_load_lds( \
    (const __attribute__((address_space(1))) unsigned int*)(gsrc), \
    (__attribute__((address_space(3))) unsigned int*)(ldst), 16, 0, 0)

__device__ __forceinline__ ushort f2bf(float f){
    union { float f; unsigned u; } v; v.f = f;
    unsigned r = (v.u + 0x7fffu + ((v.u >> 16) & 1u)) >> 16;
    return (ushort)r;
}
__device__ __forceinline__ float bf2f(ushort u){
    union { unsigned u; float f; } v; v.u = ((unsigned)u) << 16;
    return v.f;
}

// ---------------- Layer 1: Cin=1 -> 40 real (stored 64, pad zero), direct fp32 ----------
__global__ __launch_bounds__(256) void conv_l1(
    const float* __restrict__ x, const float* __restrict__ w,
    const float* __restrict__ bias, ushort* __restrict__ out)
{
    __shared__ float xs[2916];     // [3][3][18][18] padded neighborhood
    __shared__ float wsh[3240];    // [40][81]
    const int tid = threadIdx.x;
    const int bx = blockIdx.x;
    const int d2 = bx & 15, d1 = (bx >> 4) & 15, b = bx >> 8;
    const float* xb = x + (size_t)b * 65536;

    for (int i = tid; i < 2916; i += 256){
        int i4 = i % 18; int r1 = i / 18; int i3 = r1 % 18;
        int r2 = r1 / 18; int a2 = r2 % 3; int a1 = r2 / 3;
        int e1 = d1 + a1 - 1, e2 = d2 + a2 - 1, e3 = i3 - 1, e4 = i4 - 1;
        float v = 0.f;
        if ((unsigned)e1 < 16u && (unsigned)e2 < 16u && (unsigned)e3 < 16u && (unsigned)e4 < 16u)
            v = xb[((e1 * 16 + e2) * 16 + e3) * 16 + e4];
        xs[i] = v;
    }
    for (int i = tid; i < 3240; i += 256) wsh[i] = w[i];
    __syncthreads();

    const int d3 = tid >> 4, d4 = tid & 15;
    float acc[40];
    #pragma unroll
    for (int c = 0; c < 40; ++c) acc[c] = 0.f;

    for (int t1 = 0; t1 < 3; ++t1)
    for (int t2 = 0; t2 < 3; ++t2)
    for (int t3 = 0; t3 < 3; ++t3)
    #pragma unroll
    for (int t4 = 0; t4 < 3; ++t4){
        float xv = xs[((t1 * 3 + t2) * 18 + d3 + t3) * 18 + d4 + t4];
        int tap = ((t1 * 3 + t2) * 3 + t3) * 3 + t4;
        #pragma unroll
        for (int c = 0; c < 40; ++c) acc[c] += wsh[c * 81 + tap] * xv;
    }

    ushort* ob = out + ((size_t)bx * 256 + tid) * 64;
    #pragma unroll
    for (int c = 0; c < 40; ++c){
        float v = acc[c] + bias[c]; v = v > 0.f ? v : 0.f;
        ob[c] = f2bf(v);
    }
    #pragma unroll
    for (int c = 40; c < 64; ++c) ob[c] = 0;
}

// ---------------- Layer 6: 40 real (stored 48) -> Cout=1, direct fp32 -------------------
__global__ __launch_bounds__(256) void conv_l6(
    const ushort* __restrict__ in, const float* __restrict__ w,
    const float* __restrict__ bias, float* __restrict__ out)
{
    __shared__ float wsh[3240];    // [ci=40][81]
    const int tid = threadIdx.x;
    const int bx = blockIdx.x;
    const int d2 = bx & 15, d1 = (bx >> 4) & 15, b = bx >> 8;
    for (int i = tid; i < 3240; i += 256) wsh[i] = w[i];
    __syncthreads();

    const int d3 = tid >> 4, d4 = tid & 15;
    const ushort* inb = in + (size_t)b * 65536 * 48;
    float acc = 0.f;
    for (int t1 = 0; t1 < 3; ++t1){
        int e1 = d1 + t1 - 1; if ((unsigned)e1 >= 16u) continue;
        for (int t2 = 0; t2 < 3; ++t2){
            int e2 = d2 + t2 - 1; if ((unsigned)e2 >= 16u) continue;
            for (int t3 = 0; t3 < 3; ++t3){
                int e3 = d3 + t3 - 1; if ((unsigned)e3 >= 16u) continue;
                for (int t4 = 0; t4 < 3; ++t4){
                    int e4 = d4 + t4 - 1; if ((unsigned)e4 >= 16u) continue;
                    const ushort* p = inb + (size_t)(((e1 * 16 + e2) * 16 + e3) * 16 + e4) * 48;
                    int tap = ((t1 * 3 + t2) * 3 + t3) * 3 + t4;
                    #pragma unroll
                    for (int c8 = 0; c8 < 5; ++c8){
                        short8 v = *(const short8*)(p + c8 * 8);
                        #pragma unroll
                        for (int j = 0; j < 8; ++j)
                            acc += bf2f((ushort)v[j]) * wsh[(c8 * 8 + j) * 81 + tap];
                    }
                }
            }
        }
    }
    float v = acc + bias[0]; v = v > 0.f ? v : 0.f;
    out[(size_t)bx * 256 + tid] = v;
}

// -------- Weight repack: [co][ci][81] fp32 -> wq[strip][chunk][1024 x 16B] bf16 ---------
// chunk = ((gg*KC + kh)*3 + t3); inside: logical unit u = [t4][gk][col] of the 3-tap
// B-chunk, stored PRE-SWIZZLED at physical unit u^gk (the conflict-free involution),
// so global_load_lds with a LINEAR dest yields the swizzled LDS layout for free.
__global__ void repack_wq(const float* __restrict__ w, ushort* __restrict__ wq,
                          int cin_real, int cout_real, int kc, int cout_w, int nstrip)
{
    const int ncc = 27 * kc;                  // 9 groups * kc * 3 t3
    const int total = nstrip * ncc * 8192;
    for (int o = blockIdx.x * blockDim.x + threadIdx.x; o < total; o += gridDim.x * blockDim.x){
        const int j = o & 7;
        const int u_phys = (o >> 3) & 1023;
        const int chunk = o >> 13;
        const int strip = chunk / ncc;
        const int cc = chunk - strip * ncc;
        const int gg = cc / (kc * 3);
        const int rem = cc - gg * (kc * 3);
        const int kh = rem / 3;
        const int t3 = rem - kh * 3;
        float v = 0.f;
        if (u_phys < 12 * cout_w){
            const int per = 4 * cout_w;
            const int gk = ((u_phys % per) / cout_w) & 3;
            const int u = u_phys ^ gk;        // involution: gk(u) == gk(u_phys)
            const int t4 = u / per;
            const int rest = u - t4 * per;
            const int gk2 = rest / cout_w;
            const int col = rest - gk2 * cout_w;
            const int tap = gg * 9 + t3 * 3 + t4;
            const int ci = kh * 32 + gk2 * 8 + j;
            const int co = strip * cout_w + col;
            if (ci < cin_real && co < cout_real)
                v = w[((size_t)co * cin_real + ci) * 81 + tap];
        }
        wq[o] = f2bf(v);
    }
}

// ---------------- 16x16x32 MFMA implicit-GEMM conv layer --------------------------------
// in : [b][d1][d2][d3][d4][CIN_S]  bf16
// wq : pre-swizzled chunk layout (see repack_wq)
// out: [b][d1][d2][d3][d4][OST]    bf16; cols [CREAL,OST) zero-filled (PADC>0)
// Block: 256 thr = 4 waves; wave tile M64 x N=COUT_W (m4 x NT of 16x16x32).
// A staged as HALO plane [18][18][32ch] per (group,kh): halo cells zeroed once in the
// prologue (gloads never touch them), so the inner A-read is one UNCONDITIONAL
// ds_read_b128 -- no boundary compares / zero-fills / masked addresses in the hot loop.
// All staging via global_load_lds. m201-style step:
//   issue gloads(s+1) -> s_waitcnt vmcnt(4|8) -> s_barrier -> ds_read+MFMA -> s_barrier
template<int CIN_S, int COUT_W, int OST, int CREAL, int PADC>
__global__ __launch_bounds__(256, 2) void conv16(
    const ushort* __restrict__ in, const ushort* __restrict__ wq,
    const float* __restrict__ bias, ushort* __restrict__ out)
{
    constexpr int KC  = CIN_S / 32;            // A chunks per plane
    constexpr int NT  = COUT_W / 16;           // n-frags per wave
    constexpr int NCC = 27 * KC;               // B chunks per strip
    constexpr int AH  = 18 * 18 * 32;          // halo A chunk in shorts (10368)

    __shared__ __attribute__((aligned(16))) ushort As[2][AH];     // 2 x 20.25 KB
    __shared__ __attribute__((aligned(16))) ushort Bs[2][8192];   // 2 x 16 KB

    const int tid  = threadIdx.x;
    const int lane = tid & 63;
    const int wm   = tid >> 6;                 // 0..3 (64-row M slice)
    const int r    = lane & 15;                // A-row offset / B-col / D-col
    const int g    = lane >> 4;                // k-group / D row-group

    // grid: [strips][512 plane blocks]; XCD-aware chunked swizzle on plane index
    const int p0 = blockIdx.x;
    const int strip = p0 >> 9;
    const int pp = p0 & 511;
    const int bx = (pp & 7) * 64 + (pp >> 3);
    const int d2 = bx & 15, d1 = (bx >> 4) & 15, b = bx >> 8;
    const int co_base = strip * COUT_W;

    const ushort* inb = in + (size_t)b * 65536 * CIN_S;
    const ushort* wqs = wq + ((size_t)strip * NCC << 13);

    // valid (t1,t2) groups packed 4 bits each
    unsigned long long gpack = 0ull; int ng = 0;
    #pragma unroll
    for (int gg = 0; gg < 9; ++gg){
        const int t1 = gg / 3, t2 = gg - (gg / 3) * 3;
        if ((unsigned)(d1 + t1 - 1) < 16u && (unsigned)(d2 + t2 - 1) < 16u){
            gpack |= ((unsigned long long)gg) << (ng * 4);
            ++ng;
        }
    }
    const int nchunk = ng * KC;
    const int nstep  = nchunk * 3;

    f32x4 acc[4][NT];
    #pragma unroll
    for (int mi = 0; mi < 4; ++mi)
        #pragma unroll
        for (int n = 0; n < NT; ++n)
            acc[mi][n] = (f32x4){0.f, 0.f, 0.f, 0.f};

    const int ubase = (tid >> 6) * 256;        // wave-uniform
    const int ul = tid & 63;

    // B chunk: 1024 x 16B, linear copy (pre-swizzled in wq)
    auto issueB = [&](int sn, ushort* dst){
        const int cc = sn / 3, tt = sn - cc * 3;
        const int gi = cc / KC, kh = cc - gi * KC;
        const int gg = (int)((gpack >> (gi * 4)) & 15ull);
        const ushort* src = wqs + ((size_t)((gg * KC + kh) * 3 + tt) << 13);
        #pragma unroll
        for (int k = 0; k < 4; ++k){
            const int u0 = ubase + k * 64;     // wave-uniform dest base
            GLD16(src + (size_t)(u0 + ul) * 8, dst + u0 * 8);
        }
    };
    // A chunk -> halo plane: each gload instr covers one d3-row (16 pos x 4 ch-groups);
    // dest base = interior cell (e3+1,1) of the halo; per-lane pre-swizzled SOURCE.
    auto issueA = [&](int cn, ushort* dst){
        const int gi = cn / KC, kh = cn - gi * KC;
        const int gg = (int)((gpack >> (gi * 4)) & 15ull);
        const int t1 = gg / 3, t2 = gg - t1 * 3;
        const ushort* src = inb + ((size_t)((d1 + t1 - 1) * 16 + (d2 + t2 - 1)) * 256) * CIN_S + kh * 32;
        const int e4s = ul >> 2;
        const int gcs = (ul & 3) ^ ((ul >> 3) & 3);
        #pragma unroll
        for (int k = 0; k < 4; ++k){
            const int row = wm * 4 + k;        // e3 row, wave-uniform
            GLD16(src + (size_t)(row * 16 + e4s) * CIN_S + gcs * 8,
                  dst + ((row + 1) * 18 + 1) * 32);
        }
    };

    // prologue: zero BOTH halo A buffers (halo cells stay zero forever), then stage.
    {
        const short8 z = {0, 0, 0, 0, 0, 0, 0, 0};
        short8* a0 = (short8*)As[0];
        short8* a1 = (short8*)As[1];
        for (int i = tid; i < AH / 8; i += 256){ a0[i] = z; a1[i] = z; }
    }
    asm volatile("s_waitcnt lgkmcnt(0)" ::: "memory");
    __builtin_amdgcn_s_barrier();
    issueA(0, As[0]);
    issueB(0, Bs[0]);
    asm volatile("s_waitcnt vmcnt(0)" ::: "memory");
    __builtin_amdgcn_s_barrier();
    __builtin_amdgcn_sched_barrier(0);

    int c = 0, t3 = 0;
    for (int s = 0; s < nstep; ++s){
        // issue prefetch for s+1 (and next A chunk at chunk starts)
        int nis = 0;
        if (s + 1 < nstep){ issueB(s + 1, Bs[(s + 1) & 1]); nis += 4; }
        if (t3 == 0 && c + 1 < nchunk){ issueA(c + 1, As[(c + 1) & 1]); nis += 4; }
        // counted wait: previous step's loads (for THIS step's buffers) complete;
        // the nis just-issued stay in flight across the barrier and the MFMA.
        if (nis == 8)      asm volatile("s_waitcnt vmcnt(8)" ::: "memory");
        else if (nis == 4) asm volatile("s_waitcnt vmcnt(4)" ::: "memory");
        else               asm volatile("s_waitcnt vmcnt(0)" ::: "memory");
        __builtin_amdgcn_s_barrier();
        __builtin_amdgcn_sched_barrier(0);

        // compute: 3 t4-taps x (m4 x NT) MFMA, K=32 per step; A-reads unconditional
        const ushort* Ab = As[c & 1];
        const ushort* Bb = Bs[s & 1];
        __builtin_amdgcn_s_setprio(1);
        #pragma unroll
        for (int t4 = 0; t4 < 3; ++t4){
            const int e4 = r + t4 - 1;                       // -1..16, halo-safe
            const int gsw = (g ^ ((e4 >> 1) & 3)) * 8;
            const ushort* arow = Ab + ((wm * 4 + t3) * 18 + (e4 + 1)) * 32 + gsw;
            short8 bfr[NT];
            #pragma unroll
            for (int n = 0; n < NT; ++n)
                bfr[n] = *(const short8*)(Bb + ((((t4 * 4 + g) * COUT_W + n * 16 + r) * 8) ^ (g << 3)));
            #pragma unroll
            for (int mi = 0; mi < 4; ++mi){
                const short8 af = *(const short8*)(arow + mi * (18 * 32));
                #pragma unroll
                for (int n = 0; n < NT; ++n)
                    acc[mi][n] = __builtin_amdgcn_mfma_f32_16x16x32_bf16(af, bfr[n], acc[mi][n], 0, 0, 0);
            }
        }
        __builtin_amdgcn_s_setprio(0);

        // end barrier: all readers of this step's buffers are done before any wave
        // issues the overwriting gloads at the next step's top.
        __builtin_amdgcn_sched_barrier(0);
        __builtin_amdgcn_s_barrier();
        __builtin_amdgcn_sched_barrier(0);

        ++t3; if (t3 == 3){ t3 = 0; ++c; }
    }

    // epilogue: bias + ReLU + bf16 store. D frag: col = lane&15, row = g*4 + reg
    float bv[NT];
    #pragma unroll
    for (int n = 0; n < NT; ++n){
        const int co = co_base + n * 16 + r;
        bv[n] = (co < CREAL) ? bias[co] : 0.f;
    }
    ushort* ob = out + (size_t)bx * 256 * OST;
    #pragma unroll
    for (int mi = 0; mi < 4; ++mi){
        #pragma unroll
        for (int n = 0; n < NT; ++n){
            const int co = co_base + n * 16 + r;
            #pragma unroll
            for (int j = 0; j < 4; ++j){
                const int row = 64 * wm + 16 * mi + g * 4 + j;
                float v = acc[mi][n][j] + bv[n];
                v = v > 0.f ? v : 0.f;
                ob[(size_t)row * OST + co] = f2bf(v);
            }
        }
    }
    if (PADC > 0){
        const int row = 64 * wm + lane;
        const short8 z = {0, 0, 0, 0, 0, 0, 0, 0};
        #pragma unroll
        for (int pc = 0; pc < PADC; pc += 8)
            *(short8*)(ob + (size_t)row * OST + CREAL + pc) = z;
    }
}

extern "C" void kernel_launch(void* const* d_in, const int* in_sizes, int n_in,
                              void* d_out, int out_size, void* d_ws, size_t ws_size,
                              hipStream_t stream) {
    const float* x  = (const float*)d_in[0];
    const float* w1 = (const float*)d_in[1];  const float* b1 = (const float*)d_in[2];
    const float* w2 = (const float*)d_in[3];  const float* b2 = (const float*)d_in[4];
    const float* w3 = (const float*)d_in[5];  const float* b3 = (const float*)d_in[6];
    const float* w4 = (const float*)d_in[7];  const float* b4 = (const float*)d_in[8];
    const float* w5 = (const float*)d_in[9];  const float* b5 = (const float*)d_in[10];
    const float* w6 = (const float*)d_in[11]; const float* b6 = (const float*)d_in[12];

    // workspace layout (bf16 ushorts): activations + pre-swizzled weight chunks
    ushort* bufA = (ushort*)d_ws;                       // [131072][160] : 41.9 MB
    ushort* bufB = bufA + (size_t)131072 * 160;         // [131072][96]  : 25.2 MB
    ushort* wq2  = bufB + (size_t)131072 * 96;          //  54 chunks * 8192
    ushort* wq3  = wq2 + (size_t)54  * 8192;            // 162 chunks * 8192 (2 strips)
    ushort* wq4  = wq3 + (size_t)162 * 8192;            // 135 chunks * 8192
    ushort* wq5  = wq4 + (size_t)135 * 8192;            //  81 chunks * 8192

    //                                      cin  cout  kc  cout_w  nstrip
    repack_wq<<<512, 256, 0, stream>>>(w2, wq2,  40,  80, 2, 80, 1);
    repack_wq<<<512, 256, 0, stream>>>(w3, wq3,  80, 160, 3, 80, 2);
    repack_wq<<<512, 256, 0, stream>>>(w4, wq4, 160,  80, 5, 80, 1);
    repack_wq<<<512, 256, 0, stream>>>(w5, wq5,  80,  40, 3, 48, 1);

    conv_l1<<<512, 256, 0, stream>>>(x, w1, b1, bufA);
    //       CIN_S  W   OST  CREAL PADC
    conv16<  64,   80,  96,  80,  16><<< 512, 256, 0, stream>>>(bufA, wq2, b2, bufB);
    conv16<  96,   80, 160, 160,   0><<<1024, 256, 0, stream>>>(bufB, wq3, b3, bufA);
    conv16< 160,   80,  96,  80,  16><<< 512, 256, 0, stream>>>(bufA, wq4, b4, bufB);
    conv16<  96,   48,  48,  40,   0><<< 512, 256, 0, stream>>>(bufB, wq5, b5, bufA);
    conv_l6<<<512, 256, 0, stream>>>(bufA, w6, b6, (float*)d_out);
}

// Round 13
// 812.976 us; speedup vs baseline: 1.2220x; 1.0026x over previous
//
#include <hip/hip_runtime.h>

typedef __attribute__((ext_vector_type(8))) short short8;
typedef __attribute__((ext_vector_type(4))) float f32x4;

#define GLD16(gsrc, ldst) __builtin_amdgcn_global_load_lds( \
    (const __attribute__((address_space(1))) unsigned int*)(gsrc), \
    (__attribute__((address_space(3))) unsigned int*)(ldst), 16, 0, 0)

__device__ __forceinline__ ushort f2bf(float f){
    union { float f; unsigned u; } v; v.f = f;
    unsigned r = (v.u + 0x7fffu + ((v.u >> 16) & 1u)) >> 16;
    return (ushort)r;
}
__device__ __forceinline__ float bf2f(ushort u){
    union { unsigned u; float f; } v; v.u = ((unsigned)u) << 16;
    return v.f;
}

// ---------------- Layer 1: Cin=1 -> 40 real (stored 64, pad zero), direct fp32 ----------
__global__ __launch_bounds__(256) void conv_l1(
    const float* __restrict__ x, const float* __restrict__ w,
    const float* __restrict__ bias, ushort* __restrict__ out)
{
    __shared__ float xs[2916];     // [3][3][18][18] padded neighborhood
    __shared__ float wsh[3240];    // [40][81]
    const int tid = threadIdx.x;
    const int bx = blockIdx.x;
    const int d2 = bx & 15, d1 = (bx >> 4) & 15, b = bx >> 8;
    const float* xb = x + (size_t)b * 65536;

    for (int i = tid; i < 2916; i += 256){
        int i4 = i % 18; int r1 = i / 18; int i3 = r1 % 18;
        int r2 = r1 / 18; int a2 = r2 % 3; int a1 = r2 / 3;
        int e1 = d1 + a1 - 1, e2 = d2 + a2 - 1, e3 = i3 - 1, e4 = i4 - 1;
        float v = 0.f;
        if ((unsigned)e1 < 16u && (unsigned)e2 < 16u && (unsigned)e3 < 16u && (unsigned)e4 < 16u)
            v = xb[((e1 * 16 + e2) * 16 + e3) * 16 + e4];
        xs[i] = v;
    }
    for (int i = tid; i < 3240; i += 256) wsh[i] = w[i];
    __syncthreads();

    const int d3 = tid >> 4, d4 = tid & 15;
    float acc[40];
    #pragma unroll
    for (int c = 0; c < 40; ++c) acc[c] = 0.f;

    for (int t1 = 0; t1 < 3; ++t1)
    for (int t2 = 0; t2 < 3; ++t2)
    for (int t3 = 0; t3 < 3; ++t3)
    #pragma unroll
    for (int t4 = 0; t4 < 3; ++t4){
        float xv = xs[((t1 * 3 + t2) * 18 + d3 + t3) * 18 + d4 + t4];
        int tap = ((t1 * 3 + t2) * 3 + t3) * 3 + t4;
        #pragma unroll
        for (int c = 0; c < 40; ++c) acc[c] += wsh[c * 81 + tap] * xv;
    }

    ushort* ob = out + ((size_t)bx * 256 + tid) * 64;
    #pragma unroll
    for (int c = 0; c < 40; ++c){
        float v = acc[c] + bias[c]; v = v > 0.f ? v : 0.f;
        ob[c] = f2bf(v);
    }
    #pragma unroll
    for (int c = 40; c < 64; ++c) ob[c] = 0;
}

// ---------------- Layer 6: 40 real (stored 48) -> Cout=1, direct fp32 -------------------
__global__ __launch_bounds__(256) void conv_l6(
    const ushort* __restrict__ in, const float* __restrict__ w,
    const float* __restrict__ bias, float* __restrict__ out)
{
    __shared__ float wsh[3240];    // [ci=40][81]
    const int tid = threadIdx.x;
    const int bx = blockIdx.x;
    const int d2 = bx & 15, d1 = (bx >> 4) & 15, b = bx >> 8;
    for (int i = tid; i < 3240; i += 256) wsh[i] = w[i];
    __syncthreads();

    const int d3 = tid >> 4, d4 = tid & 15;
    const ushort* inb = in + (size_t)b * 65536 * 48;
    float acc = 0.f;
    for (int t1 = 0; t1 < 3; ++t1){
        int e1 = d1 + t1 - 1; if ((unsigned)e1 >= 16u) continue;
        for (int t2 = 0; t2 < 3; ++t2){
            int e2 = d2 + t2 - 1; if ((unsigned)e2 >= 16u) continue;
            for (int t3 = 0; t3 < 3; ++t3){
                int e3 = d3 + t3 - 1; if ((unsigned)e3 >= 16u) continue;
                for (int t4 = 0; t4 < 3; ++t4){
                    int e4 = d4 + t4 - 1; if ((unsigned)e4 >= 16u) continue;
                    const ushort* p = inb + (size_t)(((e1 * 16 + e2) * 16 + e3) * 16 + e4) * 48;
                    int tap = ((t1 * 3 + t2) * 3 + t3) * 3 + t4;
                    #pragma unroll
                    for (int c8 = 0; c8 < 5; ++c8){
                        short8 v = *(const short8*)(p + c8 * 8);
                        #pragma unroll
                        for (int j = 0; j < 8; ++j)
                            acc += bf2f((ushort)v[j]) * wsh[(c8 * 8 + j) * 81 + tap];
                    }
                }
            }
        }
    }
    float v = acc + bias[0]; v = v > 0.f ? v : 0.f;
    out[(size_t)bx * 256 + tid] = v;
}

// -------- Weight repack: [co][ci][81] fp32 -> wq[strip][chunk][1024 x 16B] bf16 ---------
// chunk = ((gg*KC + kh)*3 + t3); inside: logical unit u = [t4][gk][col] of the 3-tap
// B-chunk, stored PRE-SWIZZLED at physical unit u^gk (the conflict-free involution),
// so global_load_lds with a LINEAR dest yields the swizzled LDS layout for free.
__global__ void repack_wq(const float* __restrict__ w, ushort* __restrict__ wq,
                          int cin_real, int cout_real, int kc, int cout_w, int nstrip)
{
    const int ncc = 27 * kc;                  // 9 groups * kc * 3 t3
    const int total = nstrip * ncc * 8192;
    for (int o = blockIdx.x * blockDim.x + threadIdx.x; o < total; o += gridDim.x * blockDim.x){
        const int j = o & 7;
        const int u_phys = (o >> 3) & 1023;
        const int chunk = o >> 13;
        const int strip = chunk / ncc;
        const int cc = chunk - strip * ncc;
        const int gg = cc / (kc * 3);
        const int rem = cc - gg * (kc * 3);
        const int kh = rem / 3;
        const int t3 = rem - kh * 3;
        float v = 0.f;
        if (u_phys < 12 * cout_w){
            const int per = 4 * cout_w;
            const int gk = ((u_phys % per) / cout_w) & 3;
            const int u = u_phys ^ gk;        // involution: gk(u) == gk(u_phys)
            const int t4 = u / per;
            const int rest = u - t4 * per;
            const int gk2 = rest / cout_w;
            const int col = rest - gk2 * cout_w;
            const int tap = gg * 9 + t3 * 3 + t4;
            const int ci = kh * 32 + gk2 * 8 + j;
            const int co = strip * cout_w + col;
            if (ci < cin_real && co < cout_real)
                v = w[((size_t)co * cin_real + ci) * 81 + tap];
        }
        wq[o] = f2bf(v);
    }
}

// ---------------- 16x16x32 MFMA implicit-GEMM conv layer --------------------------------
// in : [b][d1][d2][d3][d4][CIN_S]  bf16
// wq : pre-swizzled chunk layout (see repack_wq)
// out: [b][d1][d2][d3][d4][OST]    bf16; cols [CREAL,OST) zero-filled (PADC>0)
// Block: 256 thr = 4 waves; wave tile M64 x N=COUT_W (m4 x NT of 16x16x32).
// A staged as HALO plane [18][18][32ch] per (group,kh): halo cells zeroed once in the
// prologue (gloads never touch them), so the inner A-read is one UNCONDITIONAL
// ds_read_b128 -- no boundary compares / zero-fills / masked addresses in the hot loop.
// All staging via global_load_lds. m201-style step:
//   issue gloads(s+1) -> s_waitcnt vmcnt(4|8) -> s_barrier -> ds_read+MFMA -> s_barrier
template<int CIN_S, int COUT_W, int OST, int CREAL, int PADC>
__global__ __launch_bounds__(256, 2) void conv16(
    const ushort* __restrict__ in, const ushort* __restrict__ wq,
    const float* __restrict__ bias, ushort* __restrict__ out)
{
    constexpr int KC  = CIN_S / 32;            // A chunks per plane
    constexpr int NT  = COUT_W / 16;           // n-frags per wave
    constexpr int NCC = 27 * KC;               // B chunks per strip
    constexpr int AH  = 18 * 18 * 32;          // halo A chunk in shorts (10368)

    __shared__ __attribute__((aligned(16))) ushort As[2][AH];     // 2 x 20.25 KB
    __shared__ __attribute__((aligned(16))) ushort Bs[2][8192];   // 2 x 16 KB

    const int tid  = threadIdx.x;
    const int lane = tid & 63;
    const int wm   = tid >> 6;                 // 0..3 (64-row M slice)
    const int r    = lane & 15;                // A-row offset / B-col / D-col
    const int g    = lane >> 4;                // k-group / D row-group

    // grid: [strips][512 plane blocks]; XCD-aware chunked swizzle on plane index
    const int p0 = blockIdx.x;
    const int strip = p0 >> 9;
    const int pp = p0 & 511;
    const int bx = (pp & 7) * 64 + (pp >> 3);
    const int d2 = bx & 15, d1 = (bx >> 4) & 15, b = bx >> 8;
    const int co_base = strip * COUT_W;

    const ushort* inb = in + (size_t)b * 65536 * CIN_S;
    const ushort* wqs = wq + ((size_t)strip * NCC << 13);

    // valid (t1,t2) groups packed 4 bits each
    unsigned long long gpack = 0ull; int ng = 0;
    #pragma unroll
    for (int gg = 0; gg < 9; ++gg){
        const int t1 = gg / 3, t2 = gg - (gg / 3) * 3;
        if ((unsigned)(d1 + t1 - 1) < 16u && (unsigned)(d2 + t2 - 1) < 16u){
            gpack |= ((unsigned long long)gg) << (ng * 4);
            ++ng;
        }
    }
    const int nchunk = ng * KC;
    const int nstep  = nchunk * 3;

    f32x4 acc[4][NT];
    #pragma unroll
    for (int mi = 0; mi < 4; ++mi)
        #pragma unroll
        for (int n = 0; n < NT; ++n)
            acc[mi][n] = (f32x4){0.f, 0.f, 0.f, 0.f};

    const int ubase = (tid >> 6) * 256;        // wave-uniform
    const int ul = tid & 63;

    // B chunk: 1024 x 16B, linear copy (pre-swizzled in wq)
    auto issueB = [&](int sn, ushort* dst){
        const int cc = sn / 3, tt = sn - cc * 3;
        const int gi = cc / KC, kh = cc - gi * KC;
        const int gg = (int)((gpack >> (gi * 4)) & 15ull);
        const ushort* src = wqs + ((size_t)((gg * KC + kh) * 3 + tt) << 13);
        #pragma unroll
        for (int k = 0; k < 4; ++k){
            const int u0 = ubase + k * 64;     // wave-uniform dest base
            GLD16(src + (size_t)(u0 + ul) * 8, dst + u0 * 8);
        }
    };
    // A chunk -> halo plane: each gload instr covers one d3-row (16 pos x 4 ch-groups);
    // dest base = interior cell (e3+1,1) of the halo; per-lane pre-swizzled SOURCE.
    auto issueA = [&](int cn, ushort* dst){
        const int gi = cn / KC, kh = cn - gi * KC;
        const int gg = (int)((gpack >> (gi * 4)) & 15ull);
        const int t1 = gg / 3, t2 = gg - t1 * 3;
        const ushort* src = inb + ((size_t)((d1 + t1 - 1) * 16 + (d2 + t2 - 1)) * 256) * CIN_S + kh * 32;
        const int e4s = ul >> 2;
        const int gcs = (ul & 3) ^ ((ul >> 3) & 3);
        #pragma unroll
        for (int k = 0; k < 4; ++k){
            const int row = wm * 4 + k;        // e3 row, wave-uniform
            GLD16(src + (size_t)(row * 16 + e4s) * CIN_S + gcs * 8,
                  dst + ((row + 1) * 18 + 1) * 32);
        }
    };

    // prologue: zero BOTH halo A buffers (halo cells stay zero forever), then stage.
    {
        const short8 z = {0, 0, 0, 0, 0, 0, 0, 0};
        short8* a0 = (short8*)As[0];
        short8* a1 = (short8*)As[1];
        for (int i = tid; i < AH / 8; i += 256){ a0[i] = z; a1[i] = z; }
    }
    asm volatile("s_waitcnt lgkmcnt(0)" ::: "memory");
    __builtin_amdgcn_s_barrier();
    issueA(0, As[0]);
    issueB(0, Bs[0]);
    asm volatile("s_waitcnt vmcnt(0)" ::: "memory");
    __builtin_amdgcn_s_barrier();
    __builtin_amdgcn_sched_barrier(0);

    int c = 0, t3 = 0;
    for (int s = 0; s < nstep; ++s){
        // issue prefetch for s+1 (and next A chunk at chunk starts)
        int nis = 0;
        if (s + 1 < nstep){ issueB(s + 1, Bs[(s + 1) & 1]); nis += 4; }
        if (t3 == 0 && c + 1 < nchunk){ issueA(c + 1, As[(c + 1) & 1]); nis += 4; }
        // counted wait: previous step's loads (for THIS step's buffers) complete;
        // the nis just-issued stay in flight across the barrier and the MFMA.
        if (nis == 8)      asm volatile("s_waitcnt vmcnt(8)" ::: "memory");
        else if (nis == 4) asm volatile("s_waitcnt vmcnt(4)" ::: "memory");
        else               asm volatile("s_waitcnt vmcnt(0)" ::: "memory");
        __builtin_amdgcn_s_barrier();
        __builtin_amdgcn_sched_barrier(0);

        // compute: 3 t4-taps x (m4 x NT) MFMA, K=32 per step; A-reads unconditional
        const ushort* Ab = As[c & 1];
        const ushort* Bb = Bs[s & 1];
        __builtin_amdgcn_s_setprio(1);
        #pragma unroll
        for (int t4 = 0; t4 < 3; ++t4){
            const int e4 = r + t4 - 1;                       // -1..16, halo-safe
            const int gsw = (g ^ ((e4 >> 1) & 3)) * 8;
            const ushort* arow = Ab + ((wm * 4 + t3) * 18 + (e4 + 1)) * 32 + gsw;
            short8 bfr[NT];
            #pragma unroll
            for (int n = 0; n < NT; ++n)
                bfr[n] = *(const short8*)(Bb + ((((t4 * 4 + g) * COUT_W + n * 16 + r) * 8) ^ (g << 3)));
            #pragma unroll
            for (int mi = 0; mi < 4; ++mi){
                const short8 af = *(const short8*)(arow + mi * (18 * 32));
                #pragma unroll
                for (int n = 0; n < NT; ++n)
                    acc[mi][n] = __builtin_amdgcn_mfma_f32_16x16x32_bf16(af, bfr[n], acc[mi][n], 0, 0, 0);
            }
        }
        __builtin_amdgcn_s_setprio(0);

        // end barrier: all readers of this step's buffers are done before any wave
        // issues the overwriting gloads at the next step's top.
        __builtin_amdgcn_sched_barrier(0);
        __builtin_amdgcn_s_barrier();
        __builtin_amdgcn_sched_barrier(0);

        ++t3; if (t3 == 3){ t3 = 0; ++c; }
    }

    // epilogue: bias + ReLU + bf16 store. D frag: col = lane&15, row = g*4 + reg
    float bv[NT];
    #pragma unroll
    for (int n = 0; n < NT; ++n){
        const int co = co_base + n * 16 + r;
        bv[n] = (co < CREAL) ? bias[co] : 0.f;
    }
    ushort* ob = out + (size_t)bx * 256 * OST;
    #pragma unroll
    for (int mi = 0; mi < 4; ++mi){
        #pragma unroll
        for (int n = 0; n < NT; ++n){
            const int co = co_base + n * 16 + r;
            #pragma unroll
            for (int j = 0; j < 4; ++j){
                const int row = 64 * wm + 16 * mi + g * 4 + j;
                float v = acc[mi][n][j] + bv[n];
                v = v > 0.f ? v : 0.f;
                ob[(size_t)row * OST + co] = f2bf(v);
            }
        }
    }
    if (PADC > 0){
        const int row = 64 * wm + lane;
        const short8 z = {0, 0, 0, 0, 0, 0, 0, 0};
        #pragma unroll
        for (int pc = 0; pc < PADC; pc += 8)
            *(short8*)(ob + (size_t)row * OST + CREAL + pc) = z;
    }
}

extern "C" void kernel_launch(void* const* d_in, const int* in_sizes, int n_in,
                              void* d_out, int out_size, void* d_ws, size_t ws_size,
                              hipStream_t stream) {
    const float* x  = (const float*)d_in[0];
    const float* w1 = (const float*)d_in[1];  const float* b1 = (const float*)d_in[2];
    const float* w2 = (const float*)d_in[3];  const float* b2 = (const float*)d_in[4];
    const float* w3 = (const float*)d_in[5];  const float* b3 = (const float*)d_in[6];
    const float* w4 = (const float*)d_in[7];  const float* b4 = (const float*)d_in[8];
    const float* w5 = (const float*)d_in[9];  const float* b5 = (const float*)d_in[10];
    const float* w6 = (const float*)d_in[11]; const float* b6 = (const float*)d_in[12];

    // workspace layout (bf16 ushorts): activations + pre-swizzled weight chunks
    ushort* bufA = (ushort*)d_ws;                       // [131072][160] : 41.9 MB
    ushort* bufB = bufA + (size_t)131072 * 160;         // [131072][96]  : 25.2 MB
    ushort* wq2  = bufB + (size_t)131072 * 96;          //  54 chunks * 8192
    ushort* wq3  = wq2 + (size_t)54  * 8192;            // 162 chunks * 8192 (2 strips)
    ushort* wq4  = wq3 + (size_t)162 * 8192;            // 135 chunks * 8192
    ushort* wq5  = wq4 + (size_t)135 * 8192;            //  81 chunks * 8192

    //                                      cin  cout  kc  cout_w  nstrip
    repack_wq<<<512, 256, 0, stream>>>(w2, wq2,  40,  80, 2, 80, 1);
    repack_wq<<<512, 256, 0, stream>>>(w3, wq3,  80, 160, 3, 80, 2);
    repack_wq<<<512, 256, 0, stream>>>(w4, wq4, 160,  80, 5, 80, 1);
    repack_wq<<<512, 256, 0, stream>>>(w5, wq5,  80,  40, 3, 48, 1);

    conv_l1<<<512, 256, 0, stream>>>(x, w1, b1, bufA);
    //       CIN_S  W   OST  CREAL PADC
    conv16<  64,   80,  96,  80,  16><<< 512, 256, 0, stream>>>(bufA, wq2, b2, bufB);
    conv16<  96,   80, 160, 160,   0><<<1024, 256, 0, stream>>>(bufB, wq3, b3, bufA);
    conv16< 160,   80,  96,  80,  16><<< 512, 256, 0, stream>>>(bufA, wq4, b4, bufB);
    conv16<  96,   48,  48,  40,   0><<< 512, 256, 0, stream>>>(bufB, wq5, b5, bufA);
    conv_l6<<<512, 256, 0, stream>>>(bufA, w6, b6, (float*)d_out);
}